// Round 3
// baseline (743.299 us; speedup 1.0000x reference)
//
#include <hip/hip_runtime.h>

// Modulated deformable conv. B=4, CIN=COUT=256, H=W=64, KS=3, PAD=1.
// ALL inputs and the output are fp32 (reference is pure jnp.float32).
// ws layout (fp32, total ~4.1 MB):
//   om_g : [256 rows][27 ch][64 px] = 442,368 floats, bias folded in
//   w_t  : [cin*9+k][cout] = 2304 x 256 = 589,824 floats (transposed w_conv)

#define OM_N 442368

// Transpose w_conv[cout][cin*9+k] -> w_t[(cin*9+k)*256 + cout].
__global__ __launch_bounds__(256) void k_prep(
    const float* __restrict__ w_conv,
    float* __restrict__ w_t)
{
    const int t = blockIdx.x * 256 + threadIdx.x;   // grid covers 589,824 exactly
    const int cout = t / 2304;
    const int ck   = t - cout * 2304;
    w_t[ck * 256 + cout] = w_conv[t];
}

// Offset conv: one block per row r = b*64+h. 512 threads = 8 waves; wave g
// handles cin in [g*32, g*32+32). Partials reduced via LDS, bias folded in.
// om_g[r*1728 + c*64 + w].
__global__ __launch_bounds__(512) void k_offconv(
    const float* __restrict__ x,
    const float* __restrict__ w_off,
    const float* __restrict__ b_off,
    float* __restrict__ om_g)
{
    __shared__ float red[8 * 1728];   // 55.3 KB

    const int r = blockIdx.x;
    const int b = r >> 6, h = r & 63;
    const int tid = threadIdx.x;
    const int g = tid >> 6;     // wave id 0..7
    const int w = tid & 63;

    float acc[27];
#pragma unroll
    for (int c = 0; c < 27; ++c) acc[c] = 0.f;

    for (int ci = 0; ci < 32; ++ci) {
        const int cin = (g << 5) + ci;
        const float* xp = x + (((size_t)(b << 8) + cin) << 12);
        float xv[9];
#pragma unroll
        for (int dy = 0; dy < 3; ++dy) {
            const int yy = h + dy - 1;
            const bool vy = ((unsigned)yy < 64u);
#pragma unroll
            for (int dx = 0; dx < 3; ++dx) {
                const int xx = w + dx - 1;
                const bool v = vy && ((unsigned)xx < 64u);
                const int idx = v ? (yy << 6) + xx : 0;
                const float t = xp[idx];
                xv[dy * 3 + dx] = v ? t : 0.f;
            }
        }
        // w_off[c][cin][j] at c*2304 + cin*9 + j — wave-uniform addresses
        const float* wp = w_off + cin * 9;
#pragma unroll
        for (int c = 0; c < 27; ++c) {
#pragma unroll
            for (int j = 0; j < 9; ++j)
                acc[c] = fmaf(xv[j], wp[c * 2304 + j], acc[c]);
        }
    }

    float* rp = red + g * 1728 + w;
#pragma unroll
    for (int c = 0; c < 27; ++c) rp[c << 6] = acc[c];
    __syncthreads();

    for (int i = tid; i < 1728; i += 512) {
        float v = b_off[i >> 6];
#pragma unroll
        for (int g2 = 0; g2 < 8; ++g2) v += red[g2 * 1728 + i];
        om_g[(size_t)r * 1728 + i] = v;
    }
}

// Main: one block per (cout-half, row). 256 threads.
// Thread t: cout pair cp = t>>2 (2 couts), pixel quarter q = t&3 (16 pixels).
__global__ __launch_bounds__(256) void k_main(
    const float* __restrict__ x,
    const float* __restrict__ om_g,
    const float* __restrict__ w_t,
    float* __restrict__ out)
{
    __shared__ __align__(16) int4   cidx[576];
    __shared__ __align__(16) float4 cwt[576];
    __shared__ __align__(16) float  samp[576];

    const int r    = blockIdx.y;   // b*64 + h
    const int half = blockIdx.x;   // cout half
    const int b = r >> 6, h = r & 63;
    const int tid = threadIdx.x;

    // per-(tap,pixel): clamped corner indices + bilinear weights
    // (validity and sigmoid mask folded in)
    const float* om = om_g + (size_t)r * 1728;
    for (int i = tid; i < 576; i += 256) {
        const int k = i >> 6, w = i & 63;
        const int ky = k / 3, kx = k - ky * 3;
        const float dyv = om[(2 * k) * 64 + w];
        const float dxv = om[(2 * k + 1) * 64 + w];
        const float mv  = 1.f / (1.f + expf(-om[(18 + k) * 64 + w]));
        const float py = dyv + (float)(h - 1 + ky);
        const float px = dxv + (float)(w - 1 + kx);
        const float y0 = floorf(py), x0 = floorf(px);
        const float wy = py - y0,    wx = px - x0;
        const float y1 = y0 + 1.f,   x1 = x0 + 1.f;
        const float vy0 = (y0 >= 0.f && y0 <= 63.f) ? 1.f : 0.f;
        const float vy1 = (y1 >= 0.f && y1 <= 63.f) ? 1.f : 0.f;
        const float vx0 = (x0 >= 0.f && x0 <= 63.f) ? 1.f : 0.f;
        const float vx1 = (x1 >= 0.f && x1 <= 63.f) ? 1.f : 0.f;
        const int iy0 = (int)fminf(fmaxf(y0, 0.f), 63.f);
        const int iy1 = (int)fminf(fmaxf(y1, 0.f), 63.f);
        const int ix0 = (int)fminf(fmaxf(x0, 0.f), 63.f);
        const int ix1 = (int)fminf(fmaxf(x1, 0.f), 63.f);
        cidx[i] = make_int4((iy0 << 6) + ix0, (iy0 << 6) + ix1,
                            (iy1 << 6) + ix0, (iy1 << 6) + ix1);
        cwt[i] = make_float4((1.f - wy) * (1.f - wx) * mv * vy0 * vx0,
                             (1.f - wy) * wx         * mv * vy0 * vx1,
                             wy         * (1.f - wx) * mv * vy1 * vx0,
                             wy         * wx         * mv * vy1 * vx1);
    }
    __syncthreads();

    const int cp = tid >> 2, q = tid & 3;
    const int o0 = (half << 7) + (cp << 1);   // this thread's even cout
    float acc0[16], acc1[16];
#pragma unroll
    for (int p = 0; p < 16; ++p) { acc0[p] = 0.f; acc1[p] = 0.f; }

    const float* xb = x + ((size_t)(b << 8) << 12);

    for (int cin = 0; cin < 256; ++cin) {
        const float* xp = xb + ((size_t)cin << 12);
        // cooperative bilinear sampling of this cin's 9x64 values
        for (int i = tid; i < 576; i += 256) {
            const int4   ci = cidx[i];
            const float4 cw = cwt[i];
            samp[i] = cw.x * xp[ci.x] + cw.y * xp[ci.y]
                    + cw.z * xp[ci.z] + cw.w * xp[ci.w];
        }
        __syncthreads();

        // w_t[cin*2304 + k*256 + cout]; o0 even -> 8B-aligned float2 load
        const float* wp = w_t + (size_t)cin * 2304 + o0;
#pragma unroll
        for (int k = 0; k < 9; ++k) {
            const float2 wv = *(const float2*)(wp + (k << 8));
            const float4* sp = (const float4*)(samp + (k << 6) + (q << 4));
#pragma unroll
            for (int pp = 0; pp < 4; ++pp) {
                const float4 sv = sp[pp];
                acc0[pp * 4 + 0] = fmaf(sv.x, wv.x, acc0[pp * 4 + 0]);
                acc0[pp * 4 + 1] = fmaf(sv.y, wv.x, acc0[pp * 4 + 1]);
                acc0[pp * 4 + 2] = fmaf(sv.z, wv.x, acc0[pp * 4 + 2]);
                acc0[pp * 4 + 3] = fmaf(sv.w, wv.x, acc0[pp * 4 + 3]);
                acc1[pp * 4 + 0] = fmaf(sv.x, wv.y, acc1[pp * 4 + 0]);
                acc1[pp * 4 + 1] = fmaf(sv.y, wv.y, acc1[pp * 4 + 1]);
                acc1[pp * 4 + 2] = fmaf(sv.z, wv.y, acc1[pp * 4 + 2]);
                acc1[pp * 4 + 3] = fmaf(sv.w, wv.y, acc1[pp * 4 + 3]);
            }
        }
        __syncthreads();
    }

    // out[((b*256 + o)*64 + h)*64 + w]
    {
        const size_t base0 = (((size_t)b * 256 + o0) * 64 + h) * 64 + (q << 4);
        const size_t base1 = base0 + 4096;   // next cout
#pragma unroll
        for (int p = 0; p < 16; ++p) {
            out[base0 + p] = acc0[p];
            out[base1 + p] = acc1[p];
        }
    }
}

extern "C" void kernel_launch(void* const* d_in, const int* in_sizes, int n_in,
                              void* d_out, int out_size, void* d_ws, size_t ws_size,
                              hipStream_t stream) {
    const float* x      = (const float*)d_in[0];
    const float* w_off  = (const float*)d_in[1];
    const float* b_off  = (const float*)d_in[2];
    const float* w_conv = (const float*)d_in[3];
    float* out = (float*)d_out;

    float* om_g = (float*)d_ws;
    float* w_t  = (float*)d_ws + OM_N;

    hipLaunchKernelGGL(k_prep, dim3(2304), dim3(256), 0, stream, w_conv, w_t);
    hipLaunchKernelGGL(k_offconv, dim3(256), dim3(512), 0, stream,
                       x, w_off, b_off, om_g);
    hipLaunchKernelGGL(k_main, dim3(2, 256), dim3(256), 0, stream,
                       x, om_g, w_t, out);
}

// Round 4
// 359.308 us; speedup vs baseline: 2.0687x; 2.0687x over previous
//
#include <hip/hip_runtime.h>

// Modulated deformable conv, fp32 in/out. B=4, CIN=COUT=256, H=W=64, KS=3, PAD=1.
// R4: main GEMM (M=16384, N=256, K=2304) on bf16 MFMA 16x16x32.
// ws layout:
//   om_part : fp32 2 x [256 rows][27 ch][64 px] = 884,736 floats (3.54 MB)
//   w_mfma  : bf16 B-fragments, 589,824 shorts (1.18 MB)
// total 4.72 MB

#define OM_HALF 442368

using short8 = __attribute__((ext_vector_type(8))) short;
using f32x4  = __attribute__((ext_vector_type(4))) float;

__device__ inline unsigned short f2bf(float v) {
    unsigned u = __float_as_uint(v);
    unsigned r = u + 0x7fffu + ((u >> 16) & 1u);   // RNE (no NaN inputs here)
    return (unsigned short)(r >> 16);
}

// Pre-swizzle w_conv[cout][cin*9+tap] into MFMA B-fragment order (bf16):
// w_mfma[((kt*16 + nt)*64 + lane)*8 + j] = W[k = kt*32 + (lane>>4)*8 + j][n = nt*16 + (lane&15)]
__global__ __launch_bounds__(256) void k_prep_w(
    const float* __restrict__ w_conv, unsigned short* __restrict__ w_mfma)
{
    const int i = blockIdx.x * 256 + threadIdx.x;   // 589,824 exactly
    const int j    = i & 7;
    const int lane = (i >> 3) & 63;
    const int nt   = (i >> 9) & 15;
    const int kt   = i >> 13;                        // 0..71
    const int n = nt * 16 + (lane & 15);
    const int k = kt * 32 + ((lane >> 4) << 3) + j;
    w_mfma[i] = f2bf(w_conv[n * 2304 + k]);
}

// Offset conv, 2-way cin split: block (hc, r) sums cins [hc*128, hc*128+128).
// 512 thr = 8 waves; wave g handles 16 cins; LDS tree-reduce. Raw sums (no bias).
__global__ __launch_bounds__(512) void k_offconv(
    const float* __restrict__ x,
    const float* __restrict__ w_off,
    float* __restrict__ om_part)
{
    __shared__ float red[8 * 1728];   // 55.3 KB

    const int hc = blockIdx.x;        // cin half
    const int r  = blockIdx.y;
    const int b = r >> 6, h = r & 63;
    const int tid = threadIdx.x;
    const int g = tid >> 6;           // wave 0..7
    const int w = tid & 63;

    float acc[27];
#pragma unroll
    for (int c = 0; c < 27; ++c) acc[c] = 0.f;

    for (int ci = 0; ci < 16; ++ci) {
        const int cin = (hc << 7) + (g << 4) + ci;
        const float* xp = x + (((size_t)(b << 8) + cin) << 12);
        float xv[9];
#pragma unroll
        for (int dy = 0; dy < 3; ++dy) {
            const int yy = h + dy - 1;
            const bool vy = ((unsigned)yy < 64u);
#pragma unroll
            for (int dx = 0; dx < 3; ++dx) {
                const int xx = w + dx - 1;
                const bool v = vy && ((unsigned)xx < 64u);
                const int idx = v ? (yy << 6) + xx : 0;
                const float t = xp[idx];
                xv[dy * 3 + dx] = v ? t : 0.f;
            }
        }
        const float* wp = w_off + cin * 9;   // wave-uniform
#pragma unroll
        for (int c = 0; c < 27; ++c) {
#pragma unroll
            for (int j = 0; j < 9; ++j)
                acc[c] = fmaf(xv[j], wp[c * 2304 + j], acc[c]);
        }
    }

    float* rp = red + g * 1728 + w;
#pragma unroll
    for (int c = 0; c < 27; ++c) rp[c << 6] = acc[c];
    __syncthreads();

    for (int i = tid; i < 1728; i += 512) {
        float v = 0.f;
#pragma unroll
        for (int g2 = 0; g2 < 8; ++g2) v += red[g2 * 1728 + i];
        om_part[(size_t)hc * OM_HALF + (size_t)r * 1728 + i] = v;
    }
}

// Main MFMA kernel. Grid 512: block = 32 consecutive pixels (half row) x all 256 couts.
// 256 thr = 4 waves; wave wv owns couts [wv*64, wv*64+64).
// K-chunks of 288 = 32 cins x 9 taps; sampled A staged in LDS as bf16.
__global__ __launch_bounds__(256) void k_main(
    const float* __restrict__ x,
    const float* __restrict__ om_part,
    const float* __restrict__ b_off,
    const unsigned short* __restrict__ w_mfma,
    float* __restrict__ out)
{
    __shared__ short  As[32 * 296];        // 18,944 B; px stride 296 shorts (16B-mult)
    __shared__ __align__(16) int4   cidx[288];   // [tap][px32]
    __shared__ __align__(16) float4 cwt[288];

    const int m0 = blockIdx.x * 32;
    const int r  = m0 >> 6;                // row id (b*64+h)
    const int b  = m0 >> 12;
    const int h  = (m0 >> 6) & 63;
    const int wbase = m0 & 63;             // 0 or 32
    const int tid  = threadIdx.x;
    const int lane = tid & 63;
    const int wv   = tid >> 6;

    // setup: corner idx + bilinear weights (mask/validity folded), om = half0+half1+bias
    const float* om0 = om_part + (size_t)r * 1728;
    const float* om1 = om_part + OM_HALF + (size_t)r * 1728;
    for (int i = tid; i < 288; i += 256) {
        const int tap = i >> 5, px = i & 31;
        const int w = wbase + px;
        const int ky = tap / 3, kx = tap - ky * 3;
        const float dyv = om0[(2 * tap) * 64 + w] + om1[(2 * tap) * 64 + w] + b_off[2 * tap];
        const float dxv = om0[(2 * tap + 1) * 64 + w] + om1[(2 * tap + 1) * 64 + w] + b_off[2 * tap + 1];
        const float mo  = om0[(18 + tap) * 64 + w] + om1[(18 + tap) * 64 + w] + b_off[18 + tap];
        const float mv  = 1.f / (1.f + expf(-mo));
        const float py = dyv + (float)(h - 1 + ky);
        const float px_f = dxv + (float)(w - 1 + kx);
        const float y0 = floorf(py), x0 = floorf(px_f);
        const float wy = py - y0,    wx = px_f - x0;
        const float y1 = y0 + 1.f,   x1 = x0 + 1.f;
        const float vy0 = (y0 >= 0.f && y0 <= 63.f) ? 1.f : 0.f;
        const float vy1 = (y1 >= 0.f && y1 <= 63.f) ? 1.f : 0.f;
        const float vx0 = (x0 >= 0.f && x0 <= 63.f) ? 1.f : 0.f;
        const float vx1 = (x1 >= 0.f && x1 <= 63.f) ? 1.f : 0.f;
        const int iy0 = (int)fminf(fmaxf(y0, 0.f), 63.f);
        const int iy1 = (int)fminf(fmaxf(y1, 0.f), 63.f);
        const int ix0 = (int)fminf(fmaxf(x0, 0.f), 63.f);
        const int ix1 = (int)fminf(fmaxf(x1, 0.f), 63.f);
        cidx[i] = make_int4((iy0 << 6) + ix0, (iy0 << 6) + ix1,
                            (iy1 << 6) + ix0, (iy1 << 6) + ix1);
        cwt[i] = make_float4((1.f - wy) * (1.f - wx) * mv * vy0 * vx0,
                             (1.f - wy) * wx         * mv * vy0 * vx1,
                             wy         * (1.f - wx) * mv * vy1 * vx0,
                             wy         * wx         * mv * vy1 * vx1);
    }
    __syncthreads();

    f32x4 acc[2][4];
#pragma unroll
    for (int a = 0; a < 2; ++a)
#pragma unroll
        for (int c = 0; c < 4; ++c) acc[a][c] = f32x4{0.f, 0.f, 0.f, 0.f};

    const int n0   = wv << 6;          // wave's first cout
    const int px_s = tid & 31;         // sampling pixel
    const int hi   = tid >> 5;         // 0..7
    const float* xb = x + ((size_t)b << 20);
    const int quad = lane >> 4;

    for (int chunk = 0; chunk < 8; ++chunk) {
        // --- sample 32 px x 288 k into As (each thread: 9 groups of 4 consecutive k) ---
#pragma unroll
        for (int j = 0; j < 9; ++j) {
            const int kl = j * 32 + (hi << 2);
            unsigned short sv[4];
#pragma unroll
            for (int i2 = 0; i2 < 4; ++i2) {
                const int k = kl + i2;
                const int cinl = k / 9;
                const int tap  = k - cinl * 9;     // chunk*288 is a multiple of 9
                const int cin  = (chunk << 5) + cinl;
                const int4   ci = cidx[(tap << 5) + px_s];
                const float4 cw = cwt[(tap << 5) + px_s];
                const float* xp = xb + ((size_t)cin << 12);
                const float v = cw.x * xp[ci.x] + cw.y * xp[ci.y]
                              + cw.z * xp[ci.z] + cw.w * xp[ci.w];
                sv[i2] = f2bf(v);
            }
            uint2 pk;
            pk.x = (unsigned)sv[0] | ((unsigned)sv[1] << 16);
            pk.y = (unsigned)sv[2] | ((unsigned)sv[3] << 16);
            *(uint2*)&As[px_s * 296 + kl] = pk;
        }
        __syncthreads();

        // --- MFMA phase: 9 K-steps of 32 ---
#pragma unroll
        for (int kt = 0; kt < 9; ++kt) {
            const int ktg = chunk * 9 + kt;
            const short8 a0 = *(const short8*)&As[(lane & 15) * 296 + kt * 32 + quad * 8];
            const short8 a1 = *(const short8*)&As[((lane & 15) + 16) * 296 + kt * 32 + quad * 8];
            const unsigned short* wb = w_mfma + (((size_t)ktg * 16 + (n0 >> 4)) * 64 + lane) * 8;
#pragma unroll
            for (int nn = 0; nn < 4; ++nn) {
                const short8 bf = *(const short8*)(wb + nn * 512);
                acc[0][nn] = __builtin_amdgcn_mfma_f32_16x16x32_bf16(a0, bf, acc[0][nn], 0, 0, 0);
                acc[1][nn] = __builtin_amdgcn_mfma_f32_16x16x32_bf16(a1, bf, acc[1][nn], 0, 0, 0);
            }
        }
        __syncthreads();
    }

    // epilogue: C/D layout row = quad*4 + reg, col = lane&15
#pragma unroll
    for (int ms = 0; ms < 2; ++ms) {
        const int wq = wbase + ms * 16 + quad * 4;
#pragma unroll
        for (int nn = 0; nn < 4; ++nn) {
            const int n = n0 + (nn << 4) + (lane & 15);
            float* op = out + ((size_t)((b << 8) + n) << 12) + (h << 6) + wq;
            *(f32x4*)op = acc[ms][nn];
        }
    }
}

extern "C" void kernel_launch(void* const* d_in, const int* in_sizes, int n_in,
                              void* d_out, int out_size, void* d_ws, size_t ws_size,
                              hipStream_t stream) {
    const float* x      = (const float*)d_in[0];
    const float* w_off  = (const float*)d_in[1];
    const float* b_off  = (const float*)d_in[2];
    const float* w_conv = (const float*)d_in[3];
    float* out = (float*)d_out;

    float*          om_part = (float*)d_ws;
    unsigned short* w_mfma  = (unsigned short*)((float*)d_ws + 2 * OM_HALF);

    hipLaunchKernelGGL(k_prep_w, dim3(2304), dim3(256), 0, stream, w_conv, w_mfma);
    hipLaunchKernelGGL(k_offconv, dim3(2, 256), dim3(512), 0, stream,
                       x, w_off, om_part);
    hipLaunchKernelGGL(k_main, dim3(512), dim3(256), 0, stream,
                       x, om_part, b_off, w_mfma, out);
}

// Round 5
// 212.059 us; speedup vs baseline: 3.5051x; 1.6944x over previous
//
#include <hip/hip_runtime.h>

// Modulated deformable conv, fp32 in/out. B=4, CIN=COUT=256, H=W=64, KS=3, PAD=1.
// R5: single fused kernel. Phase1 = offset conv via bf16 MFMA (N=32, padded 27),
// phase2 = setup (sigmoid/bilinear weights), phase3 = main GEMM (N=256) via MFMA.
// Block = 32 px x 256 couts, 512 threads (8 waves, wave owns 32 couts).
// ws: wfrag = bf16 B-fragments for w_conv (589,824) + w_off (73,728) = 1.33 MB.

#define WOFF_FRAG_OFF 589824

using short8 = __attribute__((ext_vector_type(8))) short;
using f32x4  = __attribute__((ext_vector_type(4))) float;

__device__ inline unsigned short f2bf(float v) {
    unsigned u = __float_as_uint(v);
    unsigned r = u + 0x7fffu + ((u >> 16) & 1u);   // RNE (inputs finite)
    return (unsigned short)(r >> 16);
}

// Swizzle w_conv and w_off into MFMA B-fragment order (bf16).
// w_conv: wfrag[((kt*16+nt)*64+lane)*8+j] = Wc[k=kt*32+(lane>>4)*8+j][n=nt*16+(lane&15)]
// w_off : 2 n-tiles, n>=27 padded with 0.
__global__ __launch_bounds__(256) void k_prep(
    const float* __restrict__ w_conv,
    const float* __restrict__ w_off,
    unsigned short* __restrict__ wfrag)
{
    const int i = blockIdx.x * 256 + threadIdx.x;   // grid covers 663,552 exactly
    if (i < WOFF_FRAG_OFF) {
        const int j    = i & 7;
        const int lane = (i >> 3) & 63;
        const int nt   = (i >> 9) & 15;
        const int kt   = i >> 13;                    // 0..71
        const int n = nt * 16 + (lane & 15);
        const int k = kt * 32 + ((lane >> 4) << 3) + j;
        wfrag[i] = f2bf(w_conv[n * 2304 + k]);
    } else {
        const int i2 = i - WOFF_FRAG_OFF;
        const int j    = i2 & 7;
        const int lane = (i2 >> 3) & 63;
        const int nt   = (i2 >> 9) & 1;
        const int kt   = i2 >> 10;                   // 0..71
        const int n = nt * 16 + (lane & 15);
        const int k = kt * 32 + ((lane >> 4) << 3) + j;
        wfrag[i] = (n < 27) ? f2bf(w_off[n * 2304 + k]) : (unsigned short)0;
    }
}

__global__ __launch_bounds__(512, 4) void k_all(
    const float* __restrict__ x,
    const float* __restrict__ b_off,
    const unsigned short* __restrict__ wfrag,
    float* __restrict__ out)
{
    __shared__ short As[32 * 296];                   // 18,944 B; px stride 296 shorts
    __shared__ __align__(16) int4   cidx[288];       // [tap][px32]
    __shared__ __align__(16) float4 cwt[288];
    __shared__ __align__(16) float  om_s[32 * 32];   // [c][px]

    const int bid = blockIdx.x;
    const int sid = ((bid & 7) << 6) + (bid >> 3);   // XCD-contiguous row bands
    const int m0  = sid << 5;
    const int b   = m0 >> 12;
    const int h   = (m0 >> 6) & 63;
    const int wbase = m0 & 63;                        // 0 or 32
    const int tid  = threadIdx.x;
    const int lane = tid & 63;
    const int wv   = tid >> 6;                        // 0..7
    const int quad = lane >> 4;
    const int px_s = tid & 31;                        // staging pixel
    const int hi   = tid >> 5;                        // 0..15 (k-slab)

    const float* xb = x + ((size_t)b << 20);
    const unsigned short* woffb = wfrag + WOFF_FRAG_OFF;

    // ---------- phase 1: offset conv via MFMA (regular im2col, bf16) ----------
    f32x4 om_acc[2];
    om_acc[0] = f32x4{0.f, 0.f, 0.f, 0.f};
    om_acc[1] = f32x4{0.f, 0.f, 0.f, 0.f};
    const int nt_o = wv & 1;                          // om n-tile (waves duplicate x4)

    for (int chunk = 0; chunk < 8; ++chunk) {
        // stage: thread covers k = hi*18 + j, j=0..17 (tap = j%9 compile-time)
#pragma unroll
        for (int jj = 0; jj < 9; ++jj) {
            unsigned short sv[2];
#pragma unroll
            for (int u = 0; u < 2; ++u) {
                const int j   = jj * 2 + u;
                const int tap = (j < 9) ? j : j - 9;
                const int ky = tap / 3, kx = tap - ky * 3;
                const int cin = (chunk << 5) + (hi << 1) + (j >= 9 ? 1 : 0);
                const int yy = h + ky - 1;
                const int xx = wbase + px_s + kx - 1;
                const bool v = ((unsigned)yy < 64u) && ((unsigned)xx < 64u);
                const int idx = v ? (yy << 6) + xx : 0;
                const float t = xb[((size_t)cin << 12) + idx];
                sv[u] = f2bf(v ? t : 0.f);
            }
            *(unsigned*)&As[px_s * 296 + hi * 18 + jj * 2] =
                (unsigned)sv[0] | ((unsigned)sv[1] << 16);
        }
        __syncthreads();
#pragma unroll
        for (int kt = 0; kt < 9; ++kt) {
            const int ktg = chunk * 9 + kt;
            const short8 a0 = *(const short8*)&As[(lane & 15) * 296 + kt * 32 + quad * 8];
            const short8 a1 = *(const short8*)&As[((lane & 15) + 16) * 296 + kt * 32 + quad * 8];
            const short8 bf = *(const short8*)(woffb + (((size_t)ktg * 2 + nt_o) * 64 + lane) * 8);
            om_acc[0] = __builtin_amdgcn_mfma_f32_16x16x32_bf16(a0, bf, om_acc[0], 0, 0, 0);
            om_acc[1] = __builtin_amdgcn_mfma_f32_16x16x32_bf16(a1, bf, om_acc[1], 0, 0, 0);
        }
        __syncthreads();
    }

    // write om to LDS: C-layout row = quad*4+reg = px(local), col = lane&15
    if (wv < 2) {
#pragma unroll
        for (int ms = 0; ms < 2; ++ms) {
            const int c = (nt_o << 4) + (lane & 15);
            *(f32x4*)&om_s[c * 32 + (ms << 4) + (quad << 2)] = om_acc[ms];
        }
    }
    __syncthreads();

    // ---------- phase 2: setup corner indices + bilinear/mask weights ----------
    if (tid < 288) {
        const int tap = tid >> 5, px = tid & 31;
        const int w = wbase + px;
        const int ky = tap / 3, kx = tap - ky * 3;
        const float dyv = om_s[(2 * tap) * 32 + px] + b_off[2 * tap];
        const float dxv = om_s[(2 * tap + 1) * 32 + px] + b_off[2 * tap + 1];
        const float mo  = om_s[(18 + tap) * 32 + px] + b_off[18 + tap];
        const float mv  = 1.f / (1.f + expf(-mo));
        const float py = dyv + (float)(h - 1 + ky);
        const float pxf = dxv + (float)(w - 1 + kx);
        const float y0 = floorf(py), x0 = floorf(pxf);
        const float wy = py - y0,    wx = pxf - x0;
        const float y1 = y0 + 1.f,   x1 = x0 + 1.f;
        const float vy0 = (y0 >= 0.f && y0 <= 63.f) ? 1.f : 0.f;
        const float vy1 = (y1 >= 0.f && y1 <= 63.f) ? 1.f : 0.f;
        const float vx0 = (x0 >= 0.f && x0 <= 63.f) ? 1.f : 0.f;
        const float vx1 = (x1 >= 0.f && x1 <= 63.f) ? 1.f : 0.f;
        const int iy0 = (int)fminf(fmaxf(y0, 0.f), 63.f);
        const int iy1 = (int)fminf(fmaxf(y1, 0.f), 63.f);
        const int ix0 = (int)fminf(fmaxf(x0, 0.f), 63.f);
        const int ix1 = (int)fminf(fmaxf(x1, 0.f), 63.f);
        cidx[tid] = make_int4((iy0 << 6) + ix0, (iy0 << 6) + ix1,
                              (iy1 << 6) + ix0, (iy1 << 6) + ix1);
        cwt[tid] = make_float4((1.f - wy) * (1.f - wx) * mv * vy0 * vx0,
                               (1.f - wy) * wx         * mv * vy0 * vx1,
                               wy         * (1.f - wx) * mv * vy1 * vx0,
                               wy         * wx         * mv * vy1 * vx1);
    }
    __syncthreads();

    // ---------- phase 3: deformable sampling + main GEMM ----------
    f32x4 acc[2][2];
#pragma unroll
    for (int a = 0; a < 2; ++a)
#pragma unroll
        for (int c = 0; c < 2; ++c) acc[a][c] = f32x4{0.f, 0.f, 0.f, 0.f};

    const int n0 = wv << 5;                           // wave's first cout

    for (int chunk = 0; chunk < 8; ++chunk) {
#pragma unroll
        for (int jj = 0; jj < 9; ++jj) {
            unsigned short sv[2];
#pragma unroll
            for (int u = 0; u < 2; ++u) {
                const int j   = jj * 2 + u;
                const int tap = (j < 9) ? j : j - 9;
                const int cin = (chunk << 5) + (hi << 1) + (j >= 9 ? 1 : 0);
                const int4   ci = cidx[(tap << 5) + px_s];
                const float4 cw = cwt[(tap << 5) + px_s];
                const float* xp = xb + ((size_t)cin << 12);
                const float v = cw.x * xp[ci.x] + cw.y * xp[ci.y]
                              + cw.z * xp[ci.z] + cw.w * xp[ci.w];
                sv[u] = f2bf(v);
            }
            *(unsigned*)&As[px_s * 296 + hi * 18 + jj * 2] =
                (unsigned)sv[0] | ((unsigned)sv[1] << 16);
        }
        __syncthreads();
#pragma unroll
        for (int kt = 0; kt < 9; ++kt) {
            const int ktg = chunk * 9 + kt;
            const short8 a0 = *(const short8*)&As[(lane & 15) * 296 + kt * 32 + quad * 8];
            const short8 a1 = *(const short8*)&As[((lane & 15) + 16) * 296 + kt * 32 + quad * 8];
            const unsigned short* wb = wfrag + (((size_t)ktg * 16 + (n0 >> 4)) * 64 + lane) * 8;
#pragma unroll
            for (int nn = 0; nn < 2; ++nn) {
                const short8 bf = *(const short8*)(wb + nn * 512);
                acc[0][nn] = __builtin_amdgcn_mfma_f32_16x16x32_bf16(a0, bf, acc[0][nn], 0, 0, 0);
                acc[1][nn] = __builtin_amdgcn_mfma_f32_16x16x32_bf16(a1, bf, acc[1][nn], 0, 0, 0);
            }
        }
        __syncthreads();
    }

    // epilogue: C/D row = quad*4+reg (w within px group), col = lane&15 (cout)
#pragma unroll
    for (int ms = 0; ms < 2; ++ms) {
        const int wq = wbase + (ms << 4) + (quad << 2);
#pragma unroll
        for (int nn = 0; nn < 2; ++nn) {
            const int n = n0 + (nn << 4) + (lane & 15);
            float* op = out + (((size_t)((b << 8) + n)) << 12) + (h << 6) + wq;
            *(f32x4*)op = acc[ms][nn];
        }
    }
}

extern "C" void kernel_launch(void* const* d_in, const int* in_sizes, int n_in,
                              void* d_out, int out_size, void* d_ws, size_t ws_size,
                              hipStream_t stream) {
    const float* x      = (const float*)d_in[0];
    const float* w_off  = (const float*)d_in[1];
    const float* b_off  = (const float*)d_in[2];
    const float* w_conv = (const float*)d_in[3];
    float* out = (float*)d_out;

    unsigned short* wfrag = (unsigned short*)d_ws;   // 663,552 shorts = 1.33 MB

    hipLaunchKernelGGL(k_prep, dim3(2592), dim3(256), 0, stream,
                       w_conv, w_off, wfrag);
    hipLaunchKernelGGL(k_all, dim3(512), dim3(512), 0, stream,
                       x, b_off, wfrag, out);
}